// Round 6
// baseline (893.147 us; speedup 1.0000x reference)
//
#include <hip/hip_runtime.h>
#include <math.h>

#define NN 100000
#define NE 3200000
#define INF 384
#define HID 64
#define CAP 48
#define OVF_CAP 65536
#define NBIN 98             // bin = col >> 10 (1024 nodes per bin)
#define NREP 8              // replicas per bin (blockIdx & 7 ~ XCD id)
#define NCTR (NBIN * NREP)  // 784

typedef unsigned long long ulong64;
typedef unsigned int uint32;

__device__ inline ulong64 shfl_xor_u64(ulong64 v, int mask) {
    int lo = __shfl_xor((int)(uint32)v, mask, 64);
    int hi = __shfl_xor((int)(uint32)(v >> 32), mask, 64);
    return ((ulong64)(uint32)hi << 32) | (uint32)lo;
}

// ---------------- init: ovf_cnt, bin counters ----------------

__global__ void init_kernel(int* __restrict__ ovf_cnt, int* __restrict__ bincnt) {
    int i = blockIdx.x * blockDim.x + threadIdx.x;
    if (i < NCTR) bincnt[i] = 0;
    if (i == 0) *ovf_cnt = 0;
}

// ---------------- pass 1: per-bin histogram (LDS-aggregated) ----------------
// MUST use the exact same edge->block tiling as binscatter_kernel so the
// per-replica counts match the per-replica allocations.

__global__ __launch_bounds__(256) void binhist_kernel(const int* __restrict__ col,
                                                      int* __restrict__ bincnt) {
    __shared__ int h[NBIN];
    if (threadIdx.x < NBIN) h[threadIdx.x] = 0;
    __syncthreads();
    int rep = blockIdx.x & (NREP - 1);
    for (int base = blockIdx.x * 1024; base < NE; base += gridDim.x * 1024) {
#pragma unroll
        for (int i = 0; i < 4; i++) {
            int e = base + i * 256 + threadIdx.x;
            if (e < NE) atomicAdd(&h[col[e] >> 10], 1);
        }
    }
    __syncthreads();
    if (threadIdx.x < NBIN && h[threadIdx.x] > 0)
        atomicAdd(&bincnt[threadIdx.x * NREP + rep], h[threadIdx.x]);
}

// ---------------- pass 2: exclusive scan of 784 replica counters ----------------

__global__ __launch_bounds__(256) void binscan_kernel(const int* __restrict__ bincnt,
                                                      int* __restrict__ binbase,
                                                      int* __restrict__ bincur) {
    __shared__ int tot[256];
    int t = threadIdx.x;
    int v[4];
    int s = 0;
#pragma unroll
    for (int i = 0; i < 4; i++) {
        int idx = t * 4 + i;
        v[i] = (idx < NCTR) ? bincnt[idx] : 0;
        s += v[i];
    }
    tot[t] = s;
    __syncthreads();
    for (int off = 1; off < 256; off <<= 1) {
        int x = (t >= off) ? tot[t - off] : 0;
        __syncthreads();
        tot[t] += x;
        __syncthreads();
    }
    int run = tot[t] - s;
#pragma unroll
    for (int i = 0; i < 4; i++) {
        int idx = t * 4 + i;
        if (idx < NCTR) { binbase[idx] = run; bincur[idx] = run; }
        run += v[i];
    }
    if (t == 255) binbase[NCTR] = NE;
}

// ---------------- pass 3: scatter edges into bin replicas ----------------
// payload: [w:32][col_local:10][row:17]

__global__ __launch_bounds__(256) void binscatter_kernel(const int* __restrict__ row,
                                                         const int* __restrict__ col,
                                                         const float* __restrict__ ew,
                                                         int* __restrict__ bincur,
                                                         ulong64* __restrict__ ebin) {
    __shared__ int lhist[NBIN];
    __shared__ int lbase[NBIN];
    int tid = threadIdx.x;
    int rep = blockIdx.x & (NREP - 1);
    for (int base = blockIdx.x * 1024; base < NE; base += gridDim.x * 1024) {
        if (tid < NBIN) lhist[tid] = 0;
        __syncthreads();
        int rr[4], bb[4], rk[4];
        float w[4];
#pragma unroll
        for (int i = 0; i < 4; i++) {
            int e = base + i * 256 + tid;
            bb[i] = -1;
            if (e < NE) {
                int r = row[e];
                int c = col[e];
                w[i] = ew[e];
                bb[i] = c >> 10;
                rk[i] = atomicAdd(&lhist[bb[i]], 1);
                rr[i] = r | ((c & 1023) << 17);
            }
        }
        __syncthreads();
        if (tid < NBIN && lhist[tid] > 0)
            lbase[tid] = atomicAdd(&bincur[tid * NREP + rep], lhist[tid]);
        __syncthreads();
#pragma unroll
        for (int i = 0; i < 4; i++)
            if (bb[i] >= 0) {
                int pos = lbase[bb[i]] + rk[i];
                ebin[pos] = ((ulong64)__float_as_uint(w[i]) << 32) | (uint32)rr[i];
            }
        __syncthreads();
    }
}

// ---------------- pass 4: buckets + degree + dis + per-bucket row sort ----------------

__global__ __launch_bounds__(1024) void bucket_kernel(const int* __restrict__ binbase,
                                                      const ulong64* __restrict__ ebin,
                                                      ulong64* __restrict__ sedge,
                                                      int* __restrict__ cnt,
                                                      float* __restrict__ dis,
                                                      int* __restrict__ ovf_cnt,
                                                      int4* __restrict__ ovf) {
    __shared__ int cur[1024];
    __shared__ float sdeg[1024];
    int bin = blockIdx.x;
    int node0 = bin << 10;
    cur[threadIdx.x] = 0;
    sdeg[threadIdx.x] = 0.f;
    __syncthreads();
    int start = binbase[bin * NREP];
    int end = binbase[(bin + 1) * NREP];
    for (int i = start + threadIdx.x; i < end; i += 1024) {
        ulong64 pk = ebin[i];
        int r = (int)(pk & 0x1FFFF);
        int lc = (int)((pk >> 17) & 1023);
        uint32 wb = (uint32)(pk >> 32);
        atomicAdd(&sdeg[lc], __uint_as_float(wb));   // LDS float atomic
        int rank = atomicAdd(&cur[lc], 1);           // LDS int atomic
        int node = node0 + lc;
        if (rank < CAP) {
            sedge[(size_t)node * CAP + rank] = ((ulong64)wb << 32) | (uint32)r;
        } else {
            int o = atomicAdd(ovf_cnt, 1);
            if (o < OVF_CAP) ovf[o] = make_int4(r, node, (int)wb, 0);
        }
    }
    __syncthreads();
    {
        int node = node0 + threadIdx.x;
        if (node < NN) {
            cnt[node] = min(cur[threadIdx.x], CAP);
            dis[node] = rsqrtf(sdeg[threadIdx.x] + 1.0f);  // +1 self-loop
        }
    }
    __syncthreads();
    // per-node bucket sort by source row (ascending) for gather locality
    int lane = threadIdx.x & 63;
    int wv = threadIdx.x >> 6;  // 0..15
    for (int g = 0; g < 64; g++) {
        int node = node0 + wv * 64 + g;
        if (node >= NN) break;
        int c = min(cur[wv * 64 + g], CAP);
        if (c <= 1) continue;
        ulong64 v = 0xFFFFFFFFull;  // pad key = max row
        if (lane < c) v = sedge[(size_t)node * CAP + lane];
#pragma unroll
        for (int k = 2; k <= 64; k <<= 1) {
            for (int j = k >> 1; j > 0; j >>= 1) {
                ulong64 u = shfl_xor_u64(v, j);
                uint32 a = (uint32)v, b = (uint32)u;
                bool lower = (lane & j) == 0;
                bool asc = (lane & k) == 0;
                bool take_min = (lower == asc);
                bool swp = take_min ? (b < a) : (b > a);
                if (swp) v = u;
            }
        }
        if (lane < c) sedge[(size_t)node * CAP + lane] = v;
    }
}

// ---------------- GEMM: out[N x 64] = act(A[N x K]) @ W[K x 64] ----------------

template <int K, bool LEAKY>
__global__ __launch_bounds__(256) void gemm_kernel(const float* __restrict__ A,
                                                   const float* __restrict__ W,
                                                   float* __restrict__ out) {
    __shared__ float Xs[64][68];  // [k][node], padded
    __shared__ float Ws[64][64];  // [k][j]
    const int nb = blockIdx.x * 64;
    const int jt = threadIdx.x & 15;
    const int nt = threadIdx.x >> 4;

    float acc[4][4];
#pragma unroll
    for (int a = 0; a < 4; a++)
#pragma unroll
        for (int b = 0; b < 4; b++) acc[a][b] = 0.f;

    for (int k0 = 0; k0 < K; k0 += 64) {
#pragma unroll
        for (int l = 0; l < 4; l++) {
            int idx = threadIdx.x + l * 256;
            int r = idx >> 4;
            int c = (idx & 15) * 4;
            int gr = nb + r;
            float4 v = make_float4(0.f, 0.f, 0.f, 0.f);
            if (gr < NN) v = *(const float4*)&A[(size_t)gr * K + k0 + c];
            if (LEAKY) {
                v.x = v.x > 0.f ? v.x : 0.01f * v.x;
                v.y = v.y > 0.f ? v.y : 0.01f * v.y;
                v.z = v.z > 0.f ? v.z : 0.01f * v.z;
                v.w = v.w > 0.f ? v.w : 0.01f * v.w;
            }
            Xs[c][r] = v.x; Xs[c + 1][r] = v.y; Xs[c + 2][r] = v.z; Xs[c + 3][r] = v.w;
        }
#pragma unroll
        for (int l = 0; l < 4; l++) {
            int idx = threadIdx.x + l * 256;
            int r = idx >> 4;
            int c = (idx & 15) * 4;
            *(float4*)&Ws[r][c] = *(const float4*)&W[(size_t)(k0 + r) * HID + c];
        }
        __syncthreads();

#pragma unroll 8
        for (int k = 0; k < 64; k++) {
            float4 xv = *(const float4*)&Xs[k][nt * 4];
            float4 wv = *(const float4*)&Ws[k][jt * 4];
            float xa[4] = {xv.x, xv.y, xv.z, xv.w};
            float wa[4] = {wv.x, wv.y, wv.z, wv.w};
#pragma unroll
            for (int a = 0; a < 4; a++)
#pragma unroll
                for (int b = 0; b < 4; b++) acc[a][b] = fmaf(xa[a], wa[b], acc[a][b]);
        }
        __syncthreads();
    }

#pragma unroll
    for (int a = 0; a < 4; a++) {
        int node = nb + nt * 4 + a;
        if (node < NN) {
            float4 o = make_float4(acc[a][0], acc[a][1], acc[a][2], acc[a][3]);
            *(float4*)&out[(size_t)node * HID + jt * 4] = o;
        }
    }
}

// ---------------- bucket aggregate: wave per node, lane = feature ----------------
// norm computed inline: dis table (0.4 MB) is L2-resident.

__global__ __launch_bounds__(256) void aggregate_kernel(const int* __restrict__ cnt,
                                                        const ulong64* __restrict__ sedge,
                                                        const float* __restrict__ dis,
                                                        const float* __restrict__ h,
                                                        const float* __restrict__ bias,
                                                        float* __restrict__ out) {
    int lane = threadIdx.x & 63;
    int n = blockIdx.x * 4 + (threadIdx.x >> 6);
    if (n >= NN) return;
    int c = cnt[n];
    ulong64 pk = 0;
    if (lane < c) pk = sedge[(size_t)n * CAP + lane];
    int r_l = (int)(uint32)pk;
    float w_l = __uint_as_float((uint32)(pk >> 32));  // 0 for pad lanes
    float dn = dis[n];
    float nm_l = w_l * dn * dis[r_l];                 // norm per slot (pad -> 0)

    float acc = bias[lane] + dn * dn * h[(size_t)n * HID + lane];
    int j = 0;
    for (; j + 3 < c; j += 4) {
        int r0 = __shfl(r_l, j), r1 = __shfl(r_l, j + 1);
        int r2 = __shfl(r_l, j + 2), r3 = __shfl(r_l, j + 3);
        float w0 = __shfl(nm_l, j), w1 = __shfl(nm_l, j + 1);
        float w2 = __shfl(nm_l, j + 2), w3 = __shfl(nm_l, j + 3);
        float v0 = h[(size_t)r0 * HID + lane];
        float v1 = h[(size_t)r1 * HID + lane];
        float v2 = h[(size_t)r2 * HID + lane];
        float v3 = h[(size_t)r3 * HID + lane];
        acc = fmaf(w0, v0, acc);
        acc = fmaf(w1, v1, acc);
        acc = fmaf(w2, v2, acc);
        acc = fmaf(w3, v3, acc);
    }
    for (; j < c; j++) {
        int rj = __shfl(r_l, j);
        float wj = __shfl(nm_l, j);
        acc = fmaf(wj, h[(size_t)rj * HID + lane], acc);
    }
    out[(size_t)n * HID + lane] = acc;
}

// ---------------- overflow edges: rare, fp32 atomics ----------------

__global__ __launch_bounds__(256) void ovf_kernel(const int* __restrict__ ovf_cnt,
                                                  const int4* __restrict__ ovf,
                                                  const float* __restrict__ dis,
                                                  const float* __restrict__ h,
                                                  float* __restrict__ out) {
    int lane = threadIdx.x & 63;
    int wid = blockIdx.x * 4 + (threadIdx.x >> 6);
    int nw = gridDim.x * 4;
    int c = min(*ovf_cnt, OVF_CAP);
    for (int i = wid; i < c; i += nw) {
        int4 t = ovf[i];
        float w = __int_as_float(t.z);
        float nrm = dis[t.x] * w * dis[t.y];
        atomicAdd(&out[(size_t)t.y * HID + lane], nrm * h[(size_t)t.x * HID + lane]);
    }
}

// ---------------- MLP head + softmax (wave per node) ----------------

__global__ __launch_bounds__(256) void mlp_kernel(const float* __restrict__ agg,
                                                  const float* __restrict__ Wm1,
                                                  const float* __restrict__ bm1,
                                                  const float* __restrict__ Wm2,
                                                  const float* __restrict__ bm2,
                                                  float* __restrict__ out) {
    __shared__ float W1s[64 * 64];
    __shared__ float W2s[128];
    for (int idx = threadIdx.x * 4; idx < 64 * 64; idx += 256 * 4)
        *(float4*)&W1s[idx] = *(const float4*)&Wm1[idx];
    if (threadIdx.x < 128) W2s[threadIdx.x] = Wm2[threadIdx.x];
    __syncthreads();

    int lane = threadIdx.x & 63;
    int wid = threadIdx.x >> 6;
    int gw = blockIdx.x * 4 + wid;
    int nw = gridDim.x * 4;
    float b1v = bm1[lane];
    float b20 = bm2[0], b21 = bm2[1];
    float w20 = W2s[lane * 2], w21 = W2s[lane * 2 + 1];

    for (int n = gw; n < NN; n += nw) {
        float hv = agg[(size_t)n * HID + lane];
        float acc = b1v;
#pragma unroll
        for (int k = 0; k < 64; k++) acc = fmaf(__shfl(hv, k), W1s[k * 64 + lane], acc);
        float u = acc > 0.f ? acc : (expf(acc) - 1.f);  // ELU
        float p0 = u * w20;
        float p1 = u * w21;
#pragma unroll
        for (int off = 32; off > 0; off >>= 1) {
            p0 += __shfl_xor(p0, off);
            p1 += __shfl_xor(p1, off);
        }
        if (lane == 0) {
            float l0 = p0 + b20, l1 = p1 + b21;
            float m = fmaxf(l0, l1);
            float e0 = expf(l0 - m), e1 = expf(l1 - m);
            float inv = 1.f / (e0 + e1);
            out[(size_t)n * 2] = e0 * inv;
            out[(size_t)n * 2 + 1] = e1 * inv;
        }
    }
}

// ---------------- launch ----------------

extern "C" void kernel_launch(void* const* d_in, const int* in_sizes, int n_in,
                              void* d_out, int out_size, void* d_ws, size_t ws_size,
                              hipStream_t stream) {
    const float* X   = (const float*)d_in[0];
    const int*   ei  = (const int*)d_in[1];
    const float* ew  = (const float*)d_in[2];
    const float* W1  = (const float*)d_in[3];
    const float* b1  = (const float*)d_in[4];
    const float* W2  = (const float*)d_in[5];
    const float* b2  = (const float*)d_in[6];
    const float* Wm1 = (const float*)d_in[7];
    const float* bm1 = (const float*)d_in[8];
    const float* Wm2 = (const float*)d_in[9];
    const float* bm2 = (const float*)d_in[10];
    const int* row = ei;
    const int* col = ei + NE;
    float* out = (float*)d_out;

    const size_t MB = 1024 * 1024;
    char* ws = (char*)d_ws;
    float*   dis     = (float*)  (ws + 0 * MB);           // NN floats (0.4 MB)
    int*     cnt     = (int*)    (ws + 1 * MB);           // NN ints   (0.4 MB)
    int*     ovf_cnt = (int*)    (ws + 3 * MB);           // 1 int
    int*     binbase = (int*)    (ws + 3 * MB + 4096);    // NCTR+1 ints
    int*     bincur  = (int*)    (ws + 3 * MB + 16384);   // NCTR ints
    int*     bincnt  = (int*)    (ws + 3 * MB + 32768);   // NCTR ints
    int4*    ovf     = (int4*)   (ws + 4 * MB);           // OVF_CAP*16 (1 MB)
    ulong64* ebin    = (ulong64*)(ws + 5 * MB);           // NE*8 = 25.6 MB
    float*   h2      = (float*)  (ws + 5 * MB);           // overlays ebin (consumed first)
    ulong64* sedge   = (ulong64*)(ws + 31 * MB);          // NN*CAP*8 = 38.4 MB
    float*   h1      = (float*)  (ws + 70 * MB);          // NN*64 (25.6 MB) -> 95.6 MB

    // ---- binned bucket build + norm ----
    init_kernel<<<(NCTR + 255) / 256, 256, 0, stream>>>(ovf_cnt, bincnt);
    binhist_kernel<<<1024, 256, 0, stream>>>(col, bincnt);
    binscan_kernel<<<1, 256, 0, stream>>>(bincnt, binbase, bincur);
    binscatter_kernel<<<1024, 256, 0, stream>>>(row, col, ew, bincur, ebin);
    bucket_kernel<<<NBIN, 1024, 0, stream>>>(binbase, ebin, sedge, cnt, dis, ovf_cnt, ovf);

    // ---- conv1 ----
    gemm_kernel<INF, false><<<(NN + 63) / 64, 256, 0, stream>>>(X, W1, h1);
    aggregate_kernel<<<(NN + 3) / 4, 256, 0, stream>>>(cnt, sedge, dis, h1, b1, h2);
    ovf_kernel<<<256, 256, 0, stream>>>(ovf_cnt, ovf, dis, h1, h2);

    // ---- conv2 ----
    gemm_kernel<HID, true><<<(NN + 63) / 64, 256, 0, stream>>>(h2, W2, h1);
    aggregate_kernel<<<(NN + 3) / 4, 256, 0, stream>>>(cnt, sedge, dis, h1, b2, h2);
    ovf_kernel<<<256, 256, 0, stream>>>(ovf_cnt, ovf, dis, h1, h2);

    // ---- MLP head + softmax ----
    mlp_kernel<<<2048, 256, 0, stream>>>(h2, Wm1, bm1, Wm2, bm2, out);
}

// Round 7
// 806.616 us; speedup vs baseline: 1.1073x; 1.1073x over previous
//
#include <hip/hip_runtime.h>
#include <math.h>

#define NN 100000
#define NE 3200000
#define INF 384
#define HID 64
#define CAP 48
#define OVF_CAP 65536
#define NBIN 98             // bin = col >> 10 (1024 nodes per bin)
#define NREP 8              // replicas per bin (blockIdx & 7 ~ XCD id)
#define NCTR (NBIN * NREP)  // 784

typedef unsigned long long ulong64;
typedef unsigned int uint32;

__device__ inline ulong64 shfl_xor_u64(ulong64 v, int mask) {
    int lo = __shfl_xor((int)(uint32)v, mask, 64);
    int hi = __shfl_xor((int)(uint32)(v >> 32), mask, 64);
    return ((ulong64)(uint32)hi << 32) | (uint32)lo;
}

// ---------------- init: ovf_cnt, bin counters ----------------

__global__ void init_kernel(int* __restrict__ ovf_cnt, int* __restrict__ bincnt) {
    int i = blockIdx.x * blockDim.x + threadIdx.x;
    if (i < NCTR) bincnt[i] = 0;
    if (i == 0) *ovf_cnt = 0;
}

// ---------------- pass 1: per-bin histogram (LDS-aggregated) ----------------
// MUST use the exact same edge->block tiling as binscatter_kernel so the
// per-replica counts match the per-replica allocations.

__global__ __launch_bounds__(256) void binhist_kernel(const int* __restrict__ col,
                                                      int* __restrict__ bincnt) {
    __shared__ int h[NBIN];
    if (threadIdx.x < NBIN) h[threadIdx.x] = 0;
    __syncthreads();
    int rep = blockIdx.x & (NREP - 1);
    for (int base = blockIdx.x * 1024; base < NE; base += gridDim.x * 1024) {
#pragma unroll
        for (int i = 0; i < 4; i++) {
            int e = base + i * 256 + threadIdx.x;
            if (e < NE) atomicAdd(&h[col[e] >> 10], 1);
        }
    }
    __syncthreads();
    if (threadIdx.x < NBIN && h[threadIdx.x] > 0)
        atomicAdd(&bincnt[threadIdx.x * NREP + rep], h[threadIdx.x]);
}

// ---------------- pass 2: exclusive scan of 784 replica counters ----------------

__global__ __launch_bounds__(256) void binscan_kernel(const int* __restrict__ bincnt,
                                                      int* __restrict__ binbase,
                                                      int* __restrict__ bincur) {
    __shared__ int tot[256];
    int t = threadIdx.x;
    int v[4];
    int s = 0;
#pragma unroll
    for (int i = 0; i < 4; i++) {
        int idx = t * 4 + i;
        v[i] = (idx < NCTR) ? bincnt[idx] : 0;
        s += v[i];
    }
    tot[t] = s;
    __syncthreads();
    for (int off = 1; off < 256; off <<= 1) {
        int x = (t >= off) ? tot[t - off] : 0;
        __syncthreads();
        tot[t] += x;
        __syncthreads();
    }
    int run = tot[t] - s;
#pragma unroll
    for (int i = 0; i < 4; i++) {
        int idx = t * 4 + i;
        if (idx < NCTR) { binbase[idx] = run; bincur[idx] = run; }
        run += v[i];
    }
    if (t == 255) binbase[NCTR] = NE;
}

// ---------------- pass 3: scatter edges into bin replicas ----------------
// payload: [w:32][col_local:10][row:17]

__global__ __launch_bounds__(256) void binscatter_kernel(const int* __restrict__ row,
                                                         const int* __restrict__ col,
                                                         const float* __restrict__ ew,
                                                         int* __restrict__ bincur,
                                                         ulong64* __restrict__ ebin) {
    __shared__ int lhist[NBIN];
    __shared__ int lbase[NBIN];
    int tid = threadIdx.x;
    int rep = blockIdx.x & (NREP - 1);
    for (int base = blockIdx.x * 1024; base < NE; base += gridDim.x * 1024) {
        if (tid < NBIN) lhist[tid] = 0;
        __syncthreads();
        int rr[4], bb[4], rk[4];
        float w[4];
#pragma unroll
        for (int i = 0; i < 4; i++) {
            int e = base + i * 256 + tid;
            bb[i] = -1;
            if (e < NE) {
                int r = row[e];
                int c = col[e];
                w[i] = ew[e];
                bb[i] = c >> 10;
                rk[i] = atomicAdd(&lhist[bb[i]], 1);
                rr[i] = r | ((c & 1023) << 17);
            }
        }
        __syncthreads();
        if (tid < NBIN && lhist[tid] > 0)
            lbase[tid] = atomicAdd(&bincur[tid * NREP + rep], lhist[tid]);
        __syncthreads();
#pragma unroll
        for (int i = 0; i < 4; i++)
            if (bb[i] >= 0) {
                int pos = lbase[bb[i]] + rk[i];
                ebin[pos] = ((ulong64)__float_as_uint(w[i]) << 32) | (uint32)rr[i];
            }
        __syncthreads();
    }
}

// ---------------- pass 4: buckets + degree + dis (no sort here) ----------------

__global__ __launch_bounds__(1024) void bucket_kernel(const int* __restrict__ binbase,
                                                      const ulong64* __restrict__ ebin,
                                                      ulong64* __restrict__ sedge,
                                                      int* __restrict__ cnt,
                                                      float* __restrict__ dis,
                                                      int* __restrict__ ovf_cnt,
                                                      int4* __restrict__ ovf) {
    __shared__ int cur[1024];
    __shared__ float sdeg[1024];
    int bin = blockIdx.x;
    int node0 = bin << 10;
    cur[threadIdx.x] = 0;
    sdeg[threadIdx.x] = 0.f;
    __syncthreads();
    int start = binbase[bin * NREP];
    int end = binbase[(bin + 1) * NREP];
    for (int i = start + threadIdx.x; i < end; i += 1024) {
        ulong64 pk = ebin[i];
        int r = (int)(pk & 0x1FFFF);
        int lc = (int)((pk >> 17) & 1023);
        uint32 wb = (uint32)(pk >> 32);
        atomicAdd(&sdeg[lc], __uint_as_float(wb));   // LDS float atomic
        int rank = atomicAdd(&cur[lc], 1);           // LDS int atomic
        int node = node0 + lc;
        if (rank < CAP) {
            sedge[(size_t)node * CAP + rank] = ((ulong64)wb << 32) | (uint32)r;
        } else {
            int o = atomicAdd(ovf_cnt, 1);
            if (o < OVF_CAP) ovf[o] = make_int4(r, node, (int)wb, 0);
        }
    }
    __syncthreads();
    int node = node0 + threadIdx.x;
    if (node < NN) {
        cnt[node] = min(cur[threadIdx.x], CAP);
        dis[node] = rsqrtf(sdeg[threadIdx.x] + 1.0f);  // +1 self-loop
    }
}

// ---------------- pass 5: per-bucket row sort (one wave per node) ----------------
// ascending source row -> concurrent waves sweep a narrow row slab of h
// (gather locality for aggregate_kernel)

__global__ __launch_bounds__(256) void sort_kernel(const int* __restrict__ cnt,
                                                   ulong64* __restrict__ sedge) {
    int lane = threadIdx.x & 63;
    int n = blockIdx.x * 4 + (threadIdx.x >> 6);
    if (n >= NN) return;
    int c = cnt[n];
    if (c <= 1) return;
    ulong64 v = 0xFFFFFFFFull;  // pad key = max row
    if (lane < c) v = sedge[(size_t)n * CAP + lane];
#pragma unroll
    for (int k = 2; k <= 64; k <<= 1) {
        for (int j = k >> 1; j > 0; j >>= 1) {
            ulong64 u = shfl_xor_u64(v, j);
            uint32 a = (uint32)v, b = (uint32)u;
            bool lower = (lane & j) == 0;
            bool asc = (lane & k) == 0;
            bool take_min = (lower == asc);
            bool swp = take_min ? (b < a) : (b > a);
            if (swp) v = u;
        }
    }
    if (lane < c) sedge[(size_t)n * CAP + lane] = v;
}

// ---------------- GEMM: out[N x 64] = act(A[N x K]) @ W[K x 64] ----------------

template <int K, bool LEAKY>
__global__ __launch_bounds__(256) void gemm_kernel(const float* __restrict__ A,
                                                   const float* __restrict__ W,
                                                   float* __restrict__ out) {
    __shared__ float Xs[64][68];  // [k][node], padded
    __shared__ float Ws[64][64];  // [k][j]
    const int nb = blockIdx.x * 64;
    const int jt = threadIdx.x & 15;
    const int nt = threadIdx.x >> 4;

    float acc[4][4];
#pragma unroll
    for (int a = 0; a < 4; a++)
#pragma unroll
        for (int b = 0; b < 4; b++) acc[a][b] = 0.f;

    for (int k0 = 0; k0 < K; k0 += 64) {
#pragma unroll
        for (int l = 0; l < 4; l++) {
            int idx = threadIdx.x + l * 256;
            int r = idx >> 4;
            int c = (idx & 15) * 4;
            int gr = nb + r;
            float4 v = make_float4(0.f, 0.f, 0.f, 0.f);
            if (gr < NN) v = *(const float4*)&A[(size_t)gr * K + k0 + c];
            if (LEAKY) {
                v.x = v.x > 0.f ? v.x : 0.01f * v.x;
                v.y = v.y > 0.f ? v.y : 0.01f * v.y;
                v.z = v.z > 0.f ? v.z : 0.01f * v.z;
                v.w = v.w > 0.f ? v.w : 0.01f * v.w;
            }
            Xs[c][r] = v.x; Xs[c + 1][r] = v.y; Xs[c + 2][r] = v.z; Xs[c + 3][r] = v.w;
        }
#pragma unroll
        for (int l = 0; l < 4; l++) {
            int idx = threadIdx.x + l * 256;
            int r = idx >> 4;
            int c = (idx & 15) * 4;
            *(float4*)&Ws[r][c] = *(const float4*)&W[(size_t)(k0 + r) * HID + c];
        }
        __syncthreads();

#pragma unroll 8
        for (int k = 0; k < 64; k++) {
            float4 xv = *(const float4*)&Xs[k][nt * 4];
            float4 wv = *(const float4*)&Ws[k][jt * 4];
            float xa[4] = {xv.x, xv.y, xv.z, xv.w};
            float wa[4] = {wv.x, wv.y, wv.z, wv.w};
#pragma unroll
            for (int a = 0; a < 4; a++)
#pragma unroll
                for (int b = 0; b < 4; b++) acc[a][b] = fmaf(xa[a], wa[b], acc[a][b]);
        }
        __syncthreads();
    }

#pragma unroll
    for (int a = 0; a < 4; a++) {
        int node = nb + nt * 4 + a;
        if (node < NN) {
            float4 o = make_float4(acc[a][0], acc[a][1], acc[a][2], acc[a][3]);
            *(float4*)&out[(size_t)node * HID + jt * 4] = o;
        }
    }
}

// ---------------- bucket aggregate: wave per node, lane = feature ----------------
// norm computed inline: dis table (0.4 MB) is L2-resident.

__global__ __launch_bounds__(256) void aggregate_kernel(const int* __restrict__ cnt,
                                                        const ulong64* __restrict__ sedge,
                                                        const float* __restrict__ dis,
                                                        const float* __restrict__ h,
                                                        const float* __restrict__ bias,
                                                        float* __restrict__ out) {
    int lane = threadIdx.x & 63;
    int n = blockIdx.x * 4 + (threadIdx.x >> 6);
    if (n >= NN) return;
    int c = cnt[n];
    ulong64 pk = 0;
    if (lane < c) pk = sedge[(size_t)n * CAP + lane];
    int r_l = (int)(uint32)pk;
    float w_l = __uint_as_float((uint32)(pk >> 32));  // 0 for pad lanes
    float dn = dis[n];
    float nm_l = w_l * dn * dis[r_l];                 // norm per slot (pad -> 0)

    float acc = bias[lane] + dn * dn * h[(size_t)n * HID + lane];
    int j = 0;
    for (; j + 3 < c; j += 4) {
        int r0 = __shfl(r_l, j), r1 = __shfl(r_l, j + 1);
        int r2 = __shfl(r_l, j + 2), r3 = __shfl(r_l, j + 3);
        float w0 = __shfl(nm_l, j), w1 = __shfl(nm_l, j + 1);
        float w2 = __shfl(nm_l, j + 2), w3 = __shfl(nm_l, j + 3);
        float v0 = h[(size_t)r0 * HID + lane];
        float v1 = h[(size_t)r1 * HID + lane];
        float v2 = h[(size_t)r2 * HID + lane];
        float v3 = h[(size_t)r3 * HID + lane];
        acc = fmaf(w0, v0, acc);
        acc = fmaf(w1, v1, acc);
        acc = fmaf(w2, v2, acc);
        acc = fmaf(w3, v3, acc);
    }
    for (; j < c; j++) {
        int rj = __shfl(r_l, j);
        float wj = __shfl(nm_l, j);
        acc = fmaf(wj, h[(size_t)rj * HID + lane], acc);
    }
    out[(size_t)n * HID + lane] = acc;
}

// ---------------- overflow edges: rare, fp32 atomics ----------------

__global__ __launch_bounds__(256) void ovf_kernel(const int* __restrict__ ovf_cnt,
                                                  const int4* __restrict__ ovf,
                                                  const float* __restrict__ dis,
                                                  const float* __restrict__ h,
                                                  float* __restrict__ out) {
    int lane = threadIdx.x & 63;
    int wid = blockIdx.x * 4 + (threadIdx.x >> 6);
    int nw = gridDim.x * 4;
    int c = min(*ovf_cnt, OVF_CAP);
    for (int i = wid; i < c; i += nw) {
        int4 t = ovf[i];
        float w = __int_as_float(t.z);
        float nrm = dis[t.x] * w * dis[t.y];
        atomicAdd(&out[(size_t)t.y * HID + lane], nrm * h[(size_t)t.x * HID + lane]);
    }
}

// ---------------- MLP head + softmax (wave per node) ----------------

__global__ __launch_bounds__(256) void mlp_kernel(const float* __restrict__ agg,
                                                  const float* __restrict__ Wm1,
                                                  const float* __restrict__ bm1,
                                                  const float* __restrict__ Wm2,
                                                  const float* __restrict__ bm2,
                                                  float* __restrict__ out) {
    __shared__ float W1s[64 * 64];
    __shared__ float W2s[128];
    for (int idx = threadIdx.x * 4; idx < 64 * 64; idx += 256 * 4)
        *(float4*)&W1s[idx] = *(const float4*)&Wm1[idx];
    if (threadIdx.x < 128) W2s[threadIdx.x] = Wm2[threadIdx.x];
    __syncthreads();

    int lane = threadIdx.x & 63;
    int wid = threadIdx.x >> 6;
    int gw = blockIdx.x * 4 + wid;
    int nw = gridDim.x * 4;
    float b1v = bm1[lane];
    float b20 = bm2[0], b21 = bm2[1];
    float w20 = W2s[lane * 2], w21 = W2s[lane * 2 + 1];

    for (int n = gw; n < NN; n += nw) {
        float hv = agg[(size_t)n * HID + lane];
        float acc = b1v;
#pragma unroll
        for (int k = 0; k < 64; k++) acc = fmaf(__shfl(hv, k), W1s[k * 64 + lane], acc);
        float u = acc > 0.f ? acc : (expf(acc) - 1.f);  // ELU
        float p0 = u * w20;
        float p1 = u * w21;
#pragma unroll
        for (int off = 32; off > 0; off >>= 1) {
            p0 += __shfl_xor(p0, off);
            p1 += __shfl_xor(p1, off);
        }
        if (lane == 0) {
            float l0 = p0 + b20, l1 = p1 + b21;
            float m = fmaxf(l0, l1);
            float e0 = expf(l0 - m), e1 = expf(l1 - m);
            float inv = 1.f / (e0 + e1);
            out[(size_t)n * 2] = e0 * inv;
            out[(size_t)n * 2 + 1] = e1 * inv;
        }
    }
}

// ---------------- launch ----------------

extern "C" void kernel_launch(void* const* d_in, const int* in_sizes, int n_in,
                              void* d_out, int out_size, void* d_ws, size_t ws_size,
                              hipStream_t stream) {
    const float* X   = (const float*)d_in[0];
    const int*   ei  = (const int*)d_in[1];
    const float* ew  = (const float*)d_in[2];
    const float* W1  = (const float*)d_in[3];
    const float* b1  = (const float*)d_in[4];
    const float* W2  = (const float*)d_in[5];
    const float* b2  = (const float*)d_in[6];
    const float* Wm1 = (const float*)d_in[7];
    const float* bm1 = (const float*)d_in[8];
    const float* Wm2 = (const float*)d_in[9];
    const float* bm2 = (const float*)d_in[10];
    const int* row = ei;
    const int* col = ei + NE;
    float* out = (float*)d_out;

    const size_t MB = 1024 * 1024;
    char* ws = (char*)d_ws;
    float*   dis     = (float*)  (ws + 0 * MB);           // NN floats (0.4 MB)
    int*     cnt     = (int*)    (ws + 1 * MB);           // NN ints   (0.4 MB)
    int*     ovf_cnt = (int*)    (ws + 3 * MB);           // 1 int
    int*     binbase = (int*)    (ws + 3 * MB + 4096);    // NCTR+1 ints
    int*     bincur  = (int*)    (ws + 3 * MB + 16384);   // NCTR ints
    int*     bincnt  = (int*)    (ws + 3 * MB + 32768);   // NCTR ints
    int4*    ovf     = (int4*)   (ws + 4 * MB);           // OVF_CAP*16 (1 MB)
    ulong64* ebin    = (ulong64*)(ws + 5 * MB);           // NE*8 = 25.6 MB
    float*   h2      = (float*)  (ws + 5 * MB);           // overlays ebin (consumed first)
    ulong64* sedge   = (ulong64*)(ws + 31 * MB);          // NN*CAP*8 = 38.4 MB
    float*   h1      = (float*)  (ws + 70 * MB);          // NN*64 (25.6 MB) -> 95.6 MB

    // ---- binned bucket build + norm ----
    init_kernel<<<(NCTR + 255) / 256, 256, 0, stream>>>(ovf_cnt, bincnt);
    binhist_kernel<<<1024, 256, 0, stream>>>(col, bincnt);
    binscan_kernel<<<1, 256, 0, stream>>>(bincnt, binbase, bincur);
    binscatter_kernel<<<1024, 256, 0, stream>>>(row, col, ew, bincur, ebin);
    bucket_kernel<<<NBIN, 1024, 0, stream>>>(binbase, ebin, sedge, cnt, dis, ovf_cnt, ovf);
    sort_kernel<<<(NN + 3) / 4, 256, 0, stream>>>(cnt, sedge);

    // ---- conv1 ----
    gemm_kernel<INF, false><<<(NN + 63) / 64, 256, 0, stream>>>(X, W1, h1);
    aggregate_kernel<<<(NN + 3) / 4, 256, 0, stream>>>(cnt, sedge, dis, h1, b1, h2);
    ovf_kernel<<<256, 256, 0, stream>>>(ovf_cnt, ovf, dis, h1, h2);

    // ---- conv2 ----
    gemm_kernel<HID, true><<<(NN + 63) / 64, 256, 0, stream>>>(h2, W2, h1);
    aggregate_kernel<<<(NN + 3) / 4, 256, 0, stream>>>(cnt, sedge, dis, h1, b2, h2);
    ovf_kernel<<<256, 256, 0, stream>>>(ovf_cnt, ovf, dis, h1, h2);

    // ---- MLP head + softmax ----
    mlp_kernel<<<2048, 256, 0, stream>>>(h2, Wm1, bm1, Wm2, bm2, out);
}

// Round 8
// 721.012 us; speedup vs baseline: 1.2387x; 1.1187x over previous
//
#include <hip/hip_runtime.h>
#include <math.h>

#define NN 100000
#define NE 3200000
#define INF 384
#define HID 64
#define CAP 48
#define OVF_CAP 65536
#define NBIN 391            // bin = col >> 8 (256 nodes per bin)
#define NREP 8              // replicas per bin (blockIdx & 7 ~ XCD id)
#define NCTR (NBIN * NREP)  // 3128
#define SCAN_VPT 13         // ceil(NCTR/256)

typedef unsigned long long ulong64;
typedef unsigned int uint32;
typedef unsigned short ushort16;

__device__ inline float bf16_to_f(uint32 us) { return __uint_as_float(us << 16); }
__device__ inline ushort16 f_to_bf16(float f) {
    uint32 u = __float_as_uint(f);
    u += 0x7FFF + ((u >> 16) & 1);  // round-to-nearest-even
    return (ushort16)(u >> 16);
}

// ---------------- init: ovf_cnt, bin counters ----------------

__global__ void init_kernel(int* __restrict__ ovf_cnt, int* __restrict__ bincnt) {
    int i = blockIdx.x * blockDim.x + threadIdx.x;
    if (i < NCTR) bincnt[i] = 0;
    if (i == 0) *ovf_cnt = 0;
}

// ---------------- pass 1: per-bin histogram (LDS-aggregated) ----------------
// MUST use the exact same edge->block tiling as binscatter_kernel so the
// per-replica counts match the per-replica allocations.

__global__ __launch_bounds__(256) void binhist_kernel(const int* __restrict__ col,
                                                      int* __restrict__ bincnt) {
    __shared__ int h[NBIN];
    for (int b = threadIdx.x; b < NBIN; b += 256) h[b] = 0;
    __syncthreads();
    int rep = blockIdx.x & (NREP - 1);
    for (int base = blockIdx.x * 1024; base < NE; base += gridDim.x * 1024) {
#pragma unroll
        for (int i = 0; i < 4; i++) {
            int e = base + i * 256 + threadIdx.x;
            if (e < NE) atomicAdd(&h[col[e] >> 8], 1);
        }
    }
    __syncthreads();
    for (int b = threadIdx.x; b < NBIN; b += 256)
        if (h[b] > 0) atomicAdd(&bincnt[b * NREP + rep], h[b]);
}

// ---------------- pass 2: exclusive scan of 3128 replica counters ----------------

__global__ __launch_bounds__(256) void binscan_kernel(const int* __restrict__ bincnt,
                                                      int* __restrict__ binbase,
                                                      int* __restrict__ bincur) {
    __shared__ int tot[256];
    int t = threadIdx.x;
    int v[SCAN_VPT];
    int s = 0;
#pragma unroll
    for (int i = 0; i < SCAN_VPT; i++) {
        int idx = t * SCAN_VPT + i;
        v[i] = (idx < NCTR) ? bincnt[idx] : 0;
        s += v[i];
    }
    tot[t] = s;
    __syncthreads();
    for (int off = 1; off < 256; off <<= 1) {
        int x = (t >= off) ? tot[t - off] : 0;
        __syncthreads();
        tot[t] += x;
        __syncthreads();
    }
    int run = tot[t] - s;
#pragma unroll
    for (int i = 0; i < SCAN_VPT; i++) {
        int idx = t * SCAN_VPT + i;
        if (idx < NCTR) { binbase[idx] = run; bincur[idx] = run; }
        run += v[i];
    }
    if (t == 255) binbase[NCTR] = NE;
}

// ---------------- pass 3: scatter edges into bin replicas ----------------
// payload: [w:32][col_local:8][row:17]

__global__ __launch_bounds__(256) void binscatter_kernel(const int* __restrict__ row,
                                                         const int* __restrict__ col,
                                                         const float* __restrict__ ew,
                                                         int* __restrict__ bincur,
                                                         ulong64* __restrict__ ebin) {
    __shared__ int lhist[NBIN];
    __shared__ int lbase[NBIN];
    int tid = threadIdx.x;
    int rep = blockIdx.x & (NREP - 1);
    for (int base = blockIdx.x * 1024; base < NE; base += gridDim.x * 1024) {
        for (int b = tid; b < NBIN; b += 256) lhist[b] = 0;
        __syncthreads();
        int rr[4], bb[4], rk[4];
        float w[4];
#pragma unroll
        for (int i = 0; i < 4; i++) {
            int e = base + i * 256 + tid;
            bb[i] = -1;
            if (e < NE) {
                int r = row[e];
                int c = col[e];
                w[i] = ew[e];
                bb[i] = c >> 8;
                rk[i] = atomicAdd(&lhist[bb[i]], 1);
                rr[i] = r | ((c & 255) << 17);
            }
        }
        __syncthreads();
        for (int b = tid; b < NBIN; b += 256)
            if (lhist[b] > 0) lbase[b] = atomicAdd(&bincur[b * NREP + rep], lhist[b]);
        __syncthreads();
#pragma unroll
        for (int i = 0; i < 4; i++)
            if (bb[i] >= 0) {
                int pos = lbase[bb[i]] + rk[i];
                ebin[pos] = ((ulong64)__float_as_uint(w[i]) << 32) | (uint32)rr[i];
            }
        __syncthreads();
    }
}

// ---------------- pass 4: buckets + degree + dis (256-node bins) ----------------

__global__ __launch_bounds__(256) void bucket_kernel(const int* __restrict__ binbase,
                                                     const ulong64* __restrict__ ebin,
                                                     ulong64* __restrict__ sedge,
                                                     int* __restrict__ cnt,
                                                     float* __restrict__ dis,
                                                     int* __restrict__ ovf_cnt,
                                                     int4* __restrict__ ovf) {
    __shared__ int cur[256];
    __shared__ float sdeg[256];
    int bin = blockIdx.x;
    int node0 = bin << 8;
    cur[threadIdx.x] = 0;
    sdeg[threadIdx.x] = 0.f;
    __syncthreads();
    int start = binbase[bin * NREP];
    int end = binbase[(bin + 1) * NREP];
    for (int i = start + threadIdx.x; i < end; i += 256) {
        ulong64 pk = ebin[i];
        int r = (int)(pk & 0x1FFFF);
        int lc = (int)((pk >> 17) & 255);
        uint32 wb = (uint32)(pk >> 32);
        atomicAdd(&sdeg[lc], __uint_as_float(wb));   // LDS float atomic
        int rank = atomicAdd(&cur[lc], 1);           // LDS int atomic
        int node = node0 + lc;
        if (rank < CAP) {
            sedge[(size_t)node * CAP + rank] = ((ulong64)wb << 32) | (uint32)r;
        } else {
            int o = atomicAdd(ovf_cnt, 1);
            if (o < OVF_CAP) ovf[o] = make_int4(r, node, (int)wb, 0);
        }
    }
    __syncthreads();
    int node = node0 + threadIdx.x;
    if (node < NN) {
        cnt[node] = min(cur[threadIdx.x], CAP);
        dis[node] = rsqrtf(sdeg[threadIdx.x] + 1.0f);  // +1 self-loop
    }
}

// ---------------- GEMM: out_bf16[N x 64] = act(A[N x K]) @ W[K x 64] ----------------

template <int K, bool LEAKY>
__global__ __launch_bounds__(256) void gemm_kernel(const float* __restrict__ A,
                                                   const float* __restrict__ W,
                                                   ushort16* __restrict__ out) {
    __shared__ float Xs[64][68];  // [k][node], padded
    __shared__ float Ws[64][64];  // [k][j]
    const int nb = blockIdx.x * 64;
    const int jt = threadIdx.x & 15;
    const int nt = threadIdx.x >> 4;

    float acc[4][4];
#pragma unroll
    for (int a = 0; a < 4; a++)
#pragma unroll
        for (int b = 0; b < 4; b++) acc[a][b] = 0.f;

    for (int k0 = 0; k0 < K; k0 += 64) {
#pragma unroll
        for (int l = 0; l < 4; l++) {
            int idx = threadIdx.x + l * 256;
            int r = idx >> 4;
            int c = (idx & 15) * 4;
            int gr = nb + r;
            float4 v = make_float4(0.f, 0.f, 0.f, 0.f);
            if (gr < NN) v = *(const float4*)&A[(size_t)gr * K + k0 + c];
            if (LEAKY) {
                v.x = v.x > 0.f ? v.x : 0.01f * v.x;
                v.y = v.y > 0.f ? v.y : 0.01f * v.y;
                v.z = v.z > 0.f ? v.z : 0.01f * v.z;
                v.w = v.w > 0.f ? v.w : 0.01f * v.w;
            }
            Xs[c][r] = v.x; Xs[c + 1][r] = v.y; Xs[c + 2][r] = v.z; Xs[c + 3][r] = v.w;
        }
#pragma unroll
        for (int l = 0; l < 4; l++) {
            int idx = threadIdx.x + l * 256;
            int r = idx >> 4;
            int c = (idx & 15) * 4;
            *(float4*)&Ws[r][c] = *(const float4*)&W[(size_t)(k0 + r) * HID + c];
        }
        __syncthreads();

#pragma unroll 8
        for (int k = 0; k < 64; k++) {
            float4 xv = *(const float4*)&Xs[k][nt * 4];
            float4 wv = *(const float4*)&Ws[k][jt * 4];
            float xa[4] = {xv.x, xv.y, xv.z, xv.w};
            float wa[4] = {wv.x, wv.y, wv.z, wv.w};
#pragma unroll
            for (int a = 0; a < 4; a++)
#pragma unroll
                for (int b = 0; b < 4; b++) acc[a][b] = fmaf(xa[a], wa[b], acc[a][b]);
        }
        __syncthreads();
    }

#pragma unroll
    for (int a = 0; a < 4; a++) {
        int node = nb + nt * 4 + a;
        if (node < NN) {
            ushort4 o;
            o.x = f_to_bf16(acc[a][0]);
            o.y = f_to_bf16(acc[a][1]);
            o.z = f_to_bf16(acc[a][2]);
            o.w = f_to_bf16(acc[a][3]);
            *(ushort4*)&out[(size_t)node * HID + jt * 4] = o;
        }
    }
}

// ---------------- bucket aggregate: wave per node, lane = feature ----------------
// h is bf16 (halves random-gather bytes); accumulation fp32; dis L2-resident.

__global__ __launch_bounds__(256) void aggregate_kernel(const int* __restrict__ cnt,
                                                        const ulong64* __restrict__ sedge,
                                                        const float* __restrict__ dis,
                                                        const ushort16* __restrict__ h,
                                                        const float* __restrict__ bias,
                                                        float* __restrict__ out) {
    int lane = threadIdx.x & 63;
    int n = blockIdx.x * 4 + (threadIdx.x >> 6);
    if (n >= NN) return;
    int c = cnt[n];
    ulong64 pk = 0;
    if (lane < c) pk = sedge[(size_t)n * CAP + lane];
    int r_l = (int)(uint32)pk;
    float w_l = __uint_as_float((uint32)(pk >> 32));  // 0 for pad lanes
    float dn = dis[n];
    float nm_l = w_l * dn * dis[r_l];                 // norm per slot (pad -> 0)

    float acc = bias[lane] + dn * dn * bf16_to_f(h[(size_t)n * HID + lane]);
    int j = 0;
    for (; j + 3 < c; j += 4) {
        int r0 = __shfl(r_l, j), r1 = __shfl(r_l, j + 1);
        int r2 = __shfl(r_l, j + 2), r3 = __shfl(r_l, j + 3);
        float w0 = __shfl(nm_l, j), w1 = __shfl(nm_l, j + 1);
        float w2 = __shfl(nm_l, j + 2), w3 = __shfl(nm_l, j + 3);
        float v0 = bf16_to_f(h[(size_t)r0 * HID + lane]);
        float v1 = bf16_to_f(h[(size_t)r1 * HID + lane]);
        float v2 = bf16_to_f(h[(size_t)r2 * HID + lane]);
        float v3 = bf16_to_f(h[(size_t)r3 * HID + lane]);
        acc = fmaf(w0, v0, acc);
        acc = fmaf(w1, v1, acc);
        acc = fmaf(w2, v2, acc);
        acc = fmaf(w3, v3, acc);
    }
    for (; j < c; j++) {
        int rj = __shfl(r_l, j);
        float wj = __shfl(nm_l, j);
        acc = fmaf(wj, bf16_to_f(h[(size_t)rj * HID + lane]), acc);
    }
    out[(size_t)n * HID + lane] = acc;
}

// ---------------- overflow edges: rare, fp32 atomics ----------------

__global__ __launch_bounds__(256) void ovf_kernel(const int* __restrict__ ovf_cnt,
                                                  const int4* __restrict__ ovf,
                                                  const float* __restrict__ dis,
                                                  const ushort16* __restrict__ h,
                                                  float* __restrict__ out) {
    int lane = threadIdx.x & 63;
    int wid = blockIdx.x * 4 + (threadIdx.x >> 6);
    int nw = gridDim.x * 4;
    int c = min(*ovf_cnt, OVF_CAP);
    for (int i = wid; i < c; i += nw) {
        int4 t = ovf[i];
        float w = __int_as_float(t.z);
        float nrm = dis[t.x] * w * dis[t.y];
        atomicAdd(&out[(size_t)t.y * HID + lane],
                  nrm * bf16_to_f(h[(size_t)t.x * HID + lane]));
    }
}

// ---------------- MLP head + softmax (wave per node) ----------------

__global__ __launch_bounds__(256) void mlp_kernel(const float* __restrict__ agg,
                                                  const float* __restrict__ Wm1,
                                                  const float* __restrict__ bm1,
                                                  const float* __restrict__ Wm2,
                                                  const float* __restrict__ bm2,
                                                  float* __restrict__ out) {
    __shared__ float W1s[64 * 64];
    __shared__ float W2s[128];
    for (int idx = threadIdx.x * 4; idx < 64 * 64; idx += 256 * 4)
        *(float4*)&W1s[idx] = *(const float4*)&Wm1[idx];
    if (threadIdx.x < 128) W2s[threadIdx.x] = Wm2[threadIdx.x];
    __syncthreads();

    int lane = threadIdx.x & 63;
    int wid = threadIdx.x >> 6;
    int gw = blockIdx.x * 4 + wid;
    int nw = gridDim.x * 4;
    float b1v = bm1[lane];
    float b20 = bm2[0], b21 = bm2[1];
    float w20 = W2s[lane * 2], w21 = W2s[lane * 2 + 1];

    for (int n = gw; n < NN; n += nw) {
        float hv = agg[(size_t)n * HID + lane];
        float acc = b1v;
#pragma unroll
        for (int k = 0; k < 64; k++) acc = fmaf(__shfl(hv, k), W1s[k * 64 + lane], acc);
        float u = acc > 0.f ? acc : (expf(acc) - 1.f);  // ELU
        float p0 = u * w20;
        float p1 = u * w21;
#pragma unroll
        for (int off = 32; off > 0; off >>= 1) {
            p0 += __shfl_xor(p0, off);
            p1 += __shfl_xor(p1, off);
        }
        if (lane == 0) {
            float l0 = p0 + b20, l1 = p1 + b21;
            float m = fmaxf(l0, l1);
            float e0 = expf(l0 - m), e1 = expf(l1 - m);
            float inv = 1.f / (e0 + e1);
            out[(size_t)n * 2] = e0 * inv;
            out[(size_t)n * 2 + 1] = e1 * inv;
        }
    }
}

// ---------------- launch ----------------

extern "C" void kernel_launch(void* const* d_in, const int* in_sizes, int n_in,
                              void* d_out, int out_size, void* d_ws, size_t ws_size,
                              hipStream_t stream) {
    const float* X   = (const float*)d_in[0];
    const int*   ei  = (const int*)d_in[1];
    const float* ew  = (const float*)d_in[2];
    const float* W1  = (const float*)d_in[3];
    const float* b1  = (const float*)d_in[4];
    const float* W2  = (const float*)d_in[5];
    const float* b2  = (const float*)d_in[6];
    const float* Wm1 = (const float*)d_in[7];
    const float* bm1 = (const float*)d_in[8];
    const float* Wm2 = (const float*)d_in[9];
    const float* bm2 = (const float*)d_in[10];
    const int* row = ei;
    const int* col = ei + NE;
    float* out = (float*)d_out;

    const size_t MB = 1024 * 1024;
    const size_t KB = 1024;
    char* ws = (char*)d_ws;
    float*    dis     = (float*)   (ws + 0 * MB);           // NN floats (0.4 MB)
    int*      cnt     = (int*)     (ws + 1 * MB);           // NN ints   (0.4 MB)
    int*      ovf_cnt = (int*)     (ws + 3 * MB);           // 1 int
    int*      binbase = (int*)     (ws + 3 * MB + 4 * KB);  // NCTR+1 ints (12.5 KB)
    int*      bincur  = (int*)     (ws + 3 * MB + 20 * KB); // NCTR ints
    int*      bincnt  = (int*)     (ws + 3 * MB + 36 * KB); // NCTR ints
    int4*     ovf     = (int4*)    (ws + 4 * MB);           // OVF_CAP*16 (1 MB)
    ulong64*  ebin    = (ulong64*) (ws + 5 * MB);           // NE*8 = 25.6 MB
    float*    h2      = (float*)   (ws + 5 * MB);           // fp32, overlays ebin
    ulong64*  sedge   = (ulong64*) (ws + 31 * MB);          // NN*CAP*8 = 38.4 MB
    ushort16* h1      = (ushort16*)(ws + 70 * MB);          // NN*64 bf16 (12.8 MB)

    // ---- binned bucket build + norm ----
    init_kernel<<<(NCTR + 255) / 256, 256, 0, stream>>>(ovf_cnt, bincnt);
    binhist_kernel<<<1024, 256, 0, stream>>>(col, bincnt);
    binscan_kernel<<<1, 256, 0, stream>>>(bincnt, binbase, bincur);
    binscatter_kernel<<<1024, 256, 0, stream>>>(row, col, ew, bincur, ebin);
    bucket_kernel<<<NBIN, 256, 0, stream>>>(binbase, ebin, sedge, cnt, dis, ovf_cnt, ovf);

    // ---- conv1 ----
    gemm_kernel<INF, false><<<(NN + 63) / 64, 256, 0, stream>>>(X, W1, h1);
    aggregate_kernel<<<(NN + 3) / 4, 256, 0, stream>>>(cnt, sedge, dis, h1, b1, h2);
    ovf_kernel<<<256, 256, 0, stream>>>(ovf_cnt, ovf, dis, h1, h2);

    // ---- conv2 ----
    gemm_kernel<HID, true><<<(NN + 63) / 64, 256, 0, stream>>>(h2, W2, h1);
    aggregate_kernel<<<(NN + 3) / 4, 256, 0, stream>>>(cnt, sedge, dis, h1, b2, h2);
    ovf_kernel<<<256, 256, 0, stream>>>(ovf_cnt, ovf, dis, h1, h2);

    // ---- MLP head + softmax ----
    mlp_kernel<<<2048, 256, 0, stream>>>(h2, Wm1, bm1, Wm2, bm2, out);
}